// Round 10
// baseline (126.453 us; speedup 1.0000x reference)
//
#include <hip/hip_runtime.h>
#include <math.h>

#define B_    128
#define S_    2048
#define FEAT_ 512
#define DK_   64
#define NB    1792          // target total splits (sum n_b <= 1984 < 2048)
#define GRIDP 2048          // pass grid; blocks beyond total exit fast
#define MAXN  512           // cap splits per batch (combine e[] LDS bound)

typedef float f32x4 __attribute__((ext_vector_type(4)));

__device__ __forceinline__ float dot8(f32x4 x0, f32x4 x1, f32x4 v0, f32x4 v1) {
  float p = x0[0] * v0[0];
  p = fmaf(x0[1], v0[1], p);
  p = fmaf(x0[2], v0[2], p);
  p = fmaf(x0[3], v0[3], p);
  p = fmaf(x1[0], v1[0], p);
  p = fmaf(x1[1], v1[1], p);
  p = fmaf(x1[2], v1[2], p);
  p = fmaf(x1[3], v1[3], p);
  return p;
}

__device__ __forceinline__ float wredsum(float p) {
#pragma unroll
  for (int off = 32; off; off >>= 1) p += __shfl_xor(p, off, 64);
  return p;
}

__device__ __forceinline__ int nsplits_of(int Lb, int T) {
  if (T == 0) return 1;
  int nb = (int)(((long long)Lb * NB + (T >> 1)) / T);
  if (nb < 1) nb = 1;
  if (nb > MAXN) nb = MAXN;
  return nb;
}

// ---------------------------------------------------------------------------
// Kernel 1: v[b,f] = sum_d W_K[f,d] * (input_q[b] @ W_Q)[d]
// ---------------------------------------------------------------------------
__global__ __launch_bounds__(256) void qv_kernel(
    const float* __restrict__ input_q, const float* __restrict__ W_Q,
    const float* __restrict__ W_K, float* __restrict__ v) {
  int b = blockIdx.x;
  int tid = threadIdx.x;
  __shared__ float xq[FEAT_];
  __shared__ float part[4][DK_];
  __shared__ float qs[DK_];
  for (int f = tid; f < FEAT_; f += 256) xq[f] = input_q[b * FEAT_ + f];
  __syncthreads();
  {
    int d = tid & 63, c = tid >> 6;
    float s = 0.f;
    int f0 = c * 128;
    for (int f = f0; f < f0 + 128; ++f) s = fmaf(xq[f], W_Q[f * DK_ + d], s);
    part[c][d] = s;
  }
  __syncthreads();
  if (tid < DK_)
    qs[tid] = part[0][tid] + part[1][tid] + part[2][tid] + part[3][tid];
  __syncthreads();
  for (int f = tid; f < FEAT_; f += 256) {
    const f32x4* wk = (const f32x4*)(W_K + f * DK_);
    float s = 0.f;
#pragma unroll
    for (int d4 = 0; d4 < DK_ / 4; ++d4) {
      f32x4 w = wk[d4];
      s = fmaf(w[0], qs[d4 * 4 + 0], s);
      s = fmaf(w[1], qs[d4 * 4 + 1], s);
      s = fmaf(w[2], qs[d4 * 4 + 2], s);
      s = fmaf(w[3], qs[d4 * 4 + 3], s);
    }
    v[b * FEAT_ + f] = s;
  }
}

// ---------------------------------------------------------------------------
// Kernel 2: streaming pass with WORK-PROPORTIONAL split counts. Batch b gets
// n_b ~ L_b*NB/T splits; every split owns ~T/NB (~73) contiguous rows, so all
// 2048 blocks (and hence every CU's ~8 resident blocks) carry equal work --
// removes the 1.58x per-CU straggler that capped R2/R7. Block j == global
// split j; (b,k) found from an in-LDS prefix scan of ctx (static, no atomics).
// Loop body is the proven R2/R7 code, byte-identical math.
// ---------------------------------------------------------------------------
__global__ __launch_bounds__(256) void pass_kernel(
    const float* __restrict__ input_k, const int* __restrict__ ctx,
    const float* __restrict__ v, float* __restrict__ pm,
    float* __restrict__ pl, float* __restrict__ pacc) {
  int j = blockIdx.x;
  int tid = threadIdx.x, wave = tid >> 6, lane = tid & 63;

  __shared__ int sL[B_];
  __shared__ int sInfo[4];   // b, k, L, n_b
  __shared__ float sm[4], sl4[4];
  __shared__ float sa[4][FEAT_];

  if (tid < B_) sL[tid] = ctx[tid];
  __syncthreads();
  if (tid == 0) {
    int T = 0;
    for (int i = 0; i < B_; ++i) T += sL[i];
    int q = 0, fb = -1, fk = 0, fL = 0, fn = 1;
    for (int i = 0; i < B_; ++i) {
      int nb = nsplits_of(sL[i], T);
      if (fb < 0 && j >= q && j < q + nb) {
        fb = i; fk = j - q; fL = sL[i]; fn = nb;
      }
      q += nb;
    }
    sInfo[0] = fb; sInfo[1] = fk; sInfo[2] = fL; sInfo[3] = fn;
  }
  __syncthreads();
  int b = sInfo[0];
  if (b < 0) return;   // block beyond total splits (block-uniform)
  int k = sInfo[1], L = sInfo[2], nb = sInfo[3];

  int s0 = (int)((long long)k * L / nb);
  int s1 = (int)((long long)(k + 1) * L / nb);

  if (s0 >= s1) {  // empty (L < n_b share); combine skips e==0
    if (tid == 0) { pm[j] = -INFINITY; pl[j] = 0.f; }
    return;
  }

  const float* vb = v + b * FEAT_ + lane * 4;
  f32x4 v0 = *(const f32x4*)vb;
  f32x4 v1 = *(const f32x4*)(vb + 256);

  float m = -INFINITY, l = 0.f;
  f32x4 a0 = {0.f, 0.f, 0.f, 0.f};
  f32x4 a1 = {0.f, 0.f, 0.f, 0.f};

  const float* base = input_k + (size_t)b * S_ * FEAT_;
  int s = s0 + wave;

  // main loop: 4 rows per iteration (s, s+4, s+8, s+12)
  for (; s + 12 < s1; s += 16) {
    const float* r_ = base + (size_t)s * FEAT_ + lane * 4;
    f32x4 x0 = *(const f32x4*)(r_);
    f32x4 x1 = *(const f32x4*)(r_ + 256);
    f32x4 x2 = *(const f32x4*)(r_ + 4 * FEAT_);
    f32x4 x3 = *(const f32x4*)(r_ + 4 * FEAT_ + 256);
    f32x4 x4 = *(const f32x4*)(r_ + 8 * FEAT_);
    f32x4 x5 = *(const f32x4*)(r_ + 8 * FEAT_ + 256);
    f32x4 x6 = *(const f32x4*)(r_ + 12 * FEAT_);
    f32x4 x7 = *(const f32x4*)(r_ + 12 * FEAT_ + 256);

    float p0 = dot8(x0, x1, v0, v1);
    float p1 = dot8(x2, x3, v0, v1);
    float p2 = dot8(x4, x5, v0, v1);
    float p3 = dot8(x6, x7, v0, v1);
    p0 = wredsum(p0);
    p1 = wredsum(p1);
    p2 = wredsum(p2);
    p3 = wredsum(p3);
    float mn = fmaxf(fmaxf(fmaxf(p0, p1), fmaxf(p2, p3)), m);
    float sc = __expf(m - mn);   // first group: exp(-inf)=0
    float w0 = __expf(p0 - mn), w1 = __expf(p1 - mn);
    float w2 = __expf(p2 - mn), w3 = __expf(p3 - mn);
    l = fmaf(l, sc, (w0 + w1) + (w2 + w3));
#pragma unroll
    for (int jj = 0; jj < 4; ++jj) {
      a0[jj] = fmaf(w0, x0[jj],
               fmaf(w1, x2[jj], fmaf(w2, x4[jj], fmaf(w3, x6[jj], a0[jj] * sc))));
      a1[jj] = fmaf(w0, x1[jj],
               fmaf(w1, x3[jj], fmaf(w2, x5[jj], fmaf(w3, x7[jj], a1[jj] * sc))));
    }
    m = mn;
  }
  // tail: single row per step
  for (; s < s1; s += 4) {
    const float* r_ = base + (size_t)s * FEAT_ + lane * 4;
    f32x4 x0 = *(const f32x4*)(r_);
    f32x4 x1 = *(const f32x4*)(r_ + 256);
    float p = wredsum(dot8(x0, x1, v0, v1));
    float mn = fmaxf(m, p);
    float sc = __expf(m - mn);
    float w = __expf(p - mn);
    l = fmaf(l, sc, w);
#pragma unroll
    for (int jj = 0; jj < 4; ++jj) {
      a0[jj] = fmaf(w, x0[jj], a0[jj] * sc);
      a1[jj] = fmaf(w, x1[jj], a1[jj] * sc);
    }
    m = mn;
  }

  // cross-wave combine in LDS
  if (lane == 0) { sm[wave] = m; sl4[wave] = l; }
  *(f32x4*)&sa[wave][lane * 4] = a0;
  *(f32x4*)&sa[wave][256 + lane * 4] = a1;
  __syncthreads();

  float M = fmaxf(fmaxf(sm[0], sm[1]), fmaxf(sm[2], sm[3]));
  float e0 = __expf(sm[0] - M), e1 = __expf(sm[1] - M);
  float e2 = __expf(sm[2] - M), e3 = __expf(sm[3] - M);
  if (tid == 0) {
    pm[j] = M;
    pl[j] = e0 * sl4[0] + e1 * sl4[1] + e2 * sl4[2] + e3 * sl4[3];
  }
  for (int f = tid; f < FEAT_; f += 256)
    pacc[(size_t)j * FEAT_ + f] =
        e0 * sa[0][f] + e1 * sa[1][f] + e2 * sa[2][f] + e3 * sa[3][f];
}

// ---------------------------------------------------------------------------
// Kernel 3: combine the n_b contiguous partials [Q_b, Q_b+n_b), normalize,
// zero L==0 rows. Prefix recomputed in-LDS (same formula as pass).
// ---------------------------------------------------------------------------
__global__ __launch_bounds__(256) void combine_kernel(
    const int* __restrict__ ctx, const float* __restrict__ pm,
    const float* __restrict__ pl, const float* __restrict__ pacc,
    float* __restrict__ out) {
  int b = blockIdx.x;
  int tid = threadIdx.x;
  __shared__ int sL[B_];
  __shared__ int sQN[2];     // Q_b, n_b
  __shared__ float e[MAXN];
  __shared__ float redM[4], redL[4];
  __shared__ float inv_s;

  if (tid < B_) sL[tid] = ctx[tid];
  __syncthreads();
  if (tid == 0) {
    int T = 0;
    for (int i = 0; i < B_; ++i) T += sL[i];
    int q = 0, Qb = 0, nb_ = 1;
    for (int i = 0; i <= b; ++i) {
      int nb = nsplits_of(sL[i], T);
      if (i == b) { Qb = q; nb_ = nb; }
      q += nb;
    }
    sQN[0] = Qb; sQN[1] = nb_;
  }
  __syncthreads();
  int Q = sQN[0], n = sQN[1];
  int L = sL[b];
  if (L == 0) {
    for (int f = tid; f < FEAT_; f += 256) out[b * FEAT_ + f] = 0.f;
    return;
  }

  // block-reduce max over pm[Q..Q+n)
  float M = -INFINITY;
  for (int i = tid; i < n; i += 256) M = fmaxf(M, pm[Q + i]);
#pragma unroll
  for (int off = 32; off; off >>= 1) M = fmaxf(M, __shfl_xor(M, off, 64));
  if ((tid & 63) == 0) redM[tid >> 6] = M;
  __syncthreads();
  M = fmaxf(fmaxf(redM[0], redM[1]), fmaxf(redM[2], redM[3]));

  // e_i and block-reduce sum of e_i * pl_i
  float lw = 0.f;
  for (int i = tid; i < n; i += 256) {
    float ei = __expf(pm[Q + i] - M);   // pm=-inf (empty split) -> 0
    e[i] = ei;
    lw += ei * pl[Q + i];
  }
#pragma unroll
  for (int off = 32; off; off >>= 1) lw += __shfl_xor(lw, off, 64);
  if ((tid & 63) == 0) redL[tid >> 6] = lw;
  __syncthreads();
  if (tid == 0) {
    float lt = redL[0] + redL[1] + redL[2] + redL[3];
    inv_s = (lt > 0.f) ? 1.f / lt : 0.f;
  }
  __syncthreads();
  float inv = inv_s;

  for (int f = tid; f < FEAT_; f += 256) {
    float s = 0.f;
    for (int i = 0; i < n; ++i)
      if (e[i] > 0.f)   // block-uniform; skips never-written pacc of empties
        s = fmaf(e[i], pacc[(size_t)(Q + i) * FEAT_ + f], s);
    out[b * FEAT_ + f] = s * inv;
  }
}

extern "C" void kernel_launch(void* const* d_in, const int* in_sizes, int n_in,
                              void* d_out, int out_size, void* d_ws, size_t ws_size,
                              hipStream_t stream) {
  const float* input_k = (const float*)d_in[0];
  const float* input_q = (const float*)d_in[1];
  const int*   ctx     = (const int*)d_in[2];
  const float* W_K     = (const float*)d_in[3];
  const float* W_Q     = (const float*)d_in[4];
  float* out = (float*)d_out;

  char* ws = (char*)d_ws;
  float* v    = (float*)ws;                                   // B*FEAT
  float* pm   = (float*)(ws + (size_t)B_ * FEAT_ * sizeof(float));
  float* pl   = pm + GRIDP;
  float* pacc = pl + GRIDP;                                   // GRIDP*FEAT

  qv_kernel<<<B_, 256, 0, stream>>>(input_q, W_Q, W_K, v);
  pass_kernel<<<GRIDP, 256, 0, stream>>>(input_k, ctx, v, pm, pl, pacc);
  combine_kernel<<<B_, 256, 0, stream>>>(ctx, pm, pl, pacc, out);
}